// Round 13
// baseline (212.136 us; speedup 1.0000x reference)
//
#include <hip/hip_runtime.h>

// MTTT attention, MI355X gfx950.
// B=8, N=1024, C=1024, H=16, d=64, INNER_ITR=4, INNER_LR=1.0
//
// Algebra: inner GD loop needs only G=k^Tk/N, P=k^Tv/N, mk, mv:
//   W <- W + P - G*W - mk (x) b ;  b <- mv - mk*W   (old W,b on RHS)
// Fusion (r9): out = q·Wc_b + bc_b with Wc_{b,h} = W_{b,h} @ wp_h,
//   bc_b = b_proj + sum_c b_b[c]*wp[c,:]  — removes attn kernel + 32MB.
// r11: bc two-stage. r13: g_out 128x256 grid=256 (1 block/CU, no
//   co-residency -> ~280TF) -> 64x256/4w grid=512 (2 blocks/CU).

#define SEQ    1024
#define NBATCH 8
#define DIMC   1024
#define NHEAD  16
#define HDIM   64
#define MROWS  8192      // NBATCH*SEQ
#define NQKV   3072

typedef __attribute__((ext_vector_type(8))) __bf16 bf16x8;
typedef __attribute__((ext_vector_type(4))) float  f32x4;

__device__ __forceinline__ unsigned short f2b(float f) {
  union { float f; unsigned int u; } v; v.f = f;
  unsigned int r = (v.u + 0x7FFFu + ((v.u >> 16) & 1u)) >> 16; // RNE
  return (unsigned short)r;
}
__device__ __forceinline__ float b2f(unsigned short u) {
  union { unsigned int u; float f; } v; v.u = ((unsigned int)u) << 16;
  return v.f;
}

// async global->LDS, 16B per lane; LDS dest = wave-uniform base + lane*16
__device__ __forceinline__ void load_lds16(const void* g, void* l) {
  __builtin_amdgcn_global_load_lds(
      (__attribute__((address_space(1))) void*)(void*)(g),
      (__attribute__((address_space(3))) void*)(l), 16, 0, 0);
}

#define FENCE asm volatile("" ::: "memory")
#define BAR   __builtin_amdgcn_s_barrier()

// ---------------- fp32 -> bf16 convert (vectorized) ----------------
__global__ __launch_bounds__(256) void cvt_bf16(const float* __restrict__ in,
                                                unsigned short* __restrict__ out,
                                                int n4) {
  int i = blockIdx.x * 256 + threadIdx.x;
  if (i >= n4) return;
  float4 v = ((const float4*)in)[i];
  ushort4 o;
  o.x = f2b(v.x); o.y = f2b(v.y); o.z = f2b(v.z); o.w = f2b(v.w);
  ((ushort4*)out)[i] = o;
}

// ------------- fp32 (R x Cc) -> bf16 transposed (Cc x R) -------------
__global__ __launch_bounds__(256) void transpose_cvt(const float* __restrict__ in,
                                                     unsigned short* __restrict__ out,
                                                     int R, int Cc) {
  __shared__ unsigned short tile[32][33];
  int c0 = blockIdx.x * 32, r0 = blockIdx.y * 32;
  int tx = threadIdx.x, ty = threadIdx.y;
  for (int i = ty; i < 32; i += 8)
    tile[i][tx] = f2b(in[(size_t)(r0 + i) * Cc + c0 + tx]);
  __syncthreads();
  for (int i = ty; i < 32; i += 8)
    out[(size_t)(c0 + i) * R + r0 + tx] = tile[tx][i];
}

// =====================================================================
// Occupancy-first NT bf16 GEMM body, K fixed at 1024 (r8 structure,
// fixed swizzle).  C[m][n] = sum_k A[m][k]*BT[n][k]
//   ASTRIDE: A row stride in elements (3072 lets g_out read q-slice).
//   BMODE: 0 = bf16 out, no bias; 2 = fp32 out + per-batch bias bc[b][n].
//   PERB:  1 = BT per-batch ([b][N][K], b = m0>>10).
// Ring-3 LDS, prefetch depth 2, counted vmcnt, one barrier/iter.
// LDS(row,slot16B) = row*64 + slot*16; data chunk = slot ^ ((row>>1)&3)
// (bijective 16B-position per consecutive-8-lane group); source
// pre-swizzled; read XOR per-lane const: g4 ^ ((frow>>1)&3).
// =====================================================================
template <int BM, int BN, int WM, int WN, int ASTRIDE, int BMODE, int PERB>
__device__ __forceinline__
void gemm_r3(const unsigned short* __restrict__ A,
             const unsigned short* __restrict__ BT,
             void* __restrict__ Cout,
             const float* __restrict__ bias,
             int N, int NBN) {
  constexpr int THREADS = WM * WN * 64;
  constexpr int TR      = THREADS / 4;        // 64B rows covered per call
  constexpr int ABYTES  = BM * 64;            // A K-tile bytes
  constexpr int TBYTES  = (BM + BN) * 64;     // A+B K-tile bytes
  constexpr int CALLS   = TBYTES / (THREADS * 16);
  constexpr int NT      = 32;                 // K / 32

  extern __shared__ __align__(16) char ldsb[];

  const int tid  = threadIdx.x;
  const int lane = tid & 63, wave = tid >> 6;
  const int wr = wave / WN, wc = wave % WN;
  const int frow = lane & 15, g4 = lane >> 4;
  const int cz = (g4 ^ ((frow >> 1) & 3)) * 16;  // corrected swizzle

  // XCD-aware bijective block swizzle (gridDim.x % 8 == 0)
  const int cpx = gridDim.x >> 3;
  const int wg  = (blockIdx.x & 7) * cpx + (blockIdx.x >> 3);
  const int bm = wg / NBN, bn = wg % NBN;
  const size_t m0 = (size_t)bm * BM, n0 = (size_t)bn * BN;

  const unsigned short* BTb = PERB ? (BT + (m0 >> 10) * (size_t)(1024 * 1024)) : BT;

  // staging: thread t -> row c*TR + (t>>2), slot t&3; global chunk =
  // slot ^ ((row>>1)&3) = (t&3) ^ ((t>>3)&3)   [TR % 8 == 0]
  const int trow = tid >> 2;
  const int scol = ((tid & 3) ^ ((tid >> 3) & 3)) * 8;  // element offset
  const unsigned short* psrc[CALLS];
#pragma unroll
  for (int c = 0; c < CALLS; ++c) {
    const int rr = c * TR + trow;
    psrc[c] = (rr < BM) ? (A + (m0 + rr) * (size_t)ASTRIDE + scol)
                        : (BTb + (size_t)(n0 + rr - BM) * 1024 + scol);
  }

  f32x4 acc[4][4];
  if (BMODE == 2) {
    const float* bp = bias + (m0 >> 10) * (size_t)N;
#pragma unroll
    for (int j = 0; j < 4; ++j) {
      float4 bv = *(const float4*)&bp[n0 + wc * 64 + j * 16 + g4 * 4];
      f32x4 t; t[0] = bv.x; t[1] = bv.y; t[2] = bv.z; t[3] = bv.w;
#pragma unroll
      for (int i = 0; i < 4; ++i) acc[i][j] = t;
    }
  } else {
#pragma unroll
    for (int i = 0; i < 4; ++i)
#pragma unroll
      for (int j = 0; j < 4; ++j) acc[i][j] = f32x4{0.f, 0.f, 0.f, 0.f};
  }

  auto stage = [&](int tk, int buf) {
    char* base = ldsb + buf * TBYTES + wave * 1024;
#pragma unroll
    for (int c = 0; c < CALLS; ++c)
      load_lds16(psrc[c] + tk * 32, base + c * (THREADS * 16));
  };

  const int aoff = (wr * 64 + frow) * 64 + cz;
  const int boff = ABYTES + (wc * 64 + frow) * 64 + cz;

  // prologue: tiles 0,1 -> bufs 0,1; wait tile0 (tile1 stays in flight)
  stage(0, 0); stage(1, 1);
  asm volatile("s_waitcnt vmcnt(%0)" :: "i"(CALLS) : "memory");
  FENCE; BAR;

  int bcur = 0, bpre = 2;
#pragma unroll 1
  for (int t = 0; t < NT; ++t) {
    if (t + 2 < NT) stage(t + 2, bpre);
    const char* rb = ldsb + bcur * TBYTES;
    bf16x8 af[4], bq[4];
#pragma unroll
    for (int i = 0; i < 4; ++i) af[i] = *(const bf16x8*)(rb + aoff + i * 1024);
#pragma unroll
    for (int j = 0; j < 4; ++j) bq[j] = *(const bf16x8*)(rb + boff + j * 1024);
#pragma unroll
    for (int i = 0; i < 4; ++i)
#pragma unroll
      for (int j = 0; j < 4; ++j)
        acc[i][j] = __builtin_amdgcn_mfma_f32_16x16x32_bf16(bq[j], af[i],
                                                            acc[i][j], 0, 0, 0);
    if (t + 2 < NT) asm volatile("s_waitcnt vmcnt(%0)" :: "i"(CALLS) : "memory");
    else            asm volatile("s_waitcnt vmcnt(0)" ::: "memory");
    FENCE; BAR;
    bcur = (bcur == 2) ? 0 : bcur + 1;
    bpre = (bpre == 2) ? 0 : bpre + 1;
  }

  // epilogue: thread holds 4 consecutive output columns per acc frag
  const size_t mbase = m0 + wr * 64 + frow;
  const size_t nbase = n0 + wc * 64 + g4 * 4;
  if (BMODE == 2) {
    float* C = (float*)Cout;
#pragma unroll
    for (int i = 0; i < 4; ++i)
#pragma unroll
      for (int j = 0; j < 4; ++j) {
        float4 o; o.x = acc[i][j][0]; o.y = acc[i][j][1];
        o.z = acc[i][j][2]; o.w = acc[i][j][3];
        *(float4*)&C[(mbase + i * 16) * N + nbase + j * 16] = o;
      }
  } else {
    unsigned short* C = (unsigned short*)Cout;
#pragma unroll
    for (int i = 0; i < 4; ++i)
#pragma unroll
      for (int j = 0; j < 4; ++j) {
        ushort4 o; o.x = f2b(acc[i][j][0]); o.y = f2b(acc[i][j][1]);
        o.z = f2b(acc[i][j][2]); o.w = f2b(acc[i][j][3]);
        *(ushort4*)&C[(mbase + i * 16) * N + nbase + j * 16] = o;
      }
  }
}

__global__ __launch_bounds__(512, 4) void g_qkv(const unsigned short* __restrict__ A,
                                                const unsigned short* __restrict__ BT,
                                                void* __restrict__ C,
                                                const float* __restrict__ bias, int N, int NBN) {
  gemm_r3<128, 256, 2, 4, 1024, 0, 0>(A, BT, C, bias, N, NBN);
}
// g_out: A = q-slice of qkvb (stride 3072), B = per-batch WcT.
// BM=64 -> grid 512 (2 blocks/CU co-resident; the r12 256-block config
// had exactly 1 block/CU and no latency overlap -> ~280 TF).
__global__ __launch_bounds__(256, 4) void g_out(const unsigned short* __restrict__ A,
                                                const unsigned short* __restrict__ BT,
                                                void* __restrict__ C,
                                                const float* __restrict__ bias, int N, int NBN) {
  gemm_r3<64, 256, 1, 4, NQKV, 2, 1>(A, BT, C, bias, N, NBN);
}

// ------------- k,v: qkv layout (m, 3C) -> per-head d-major [bh][d][N] -------------
__global__ __launch_bounds__(256) void transpose_kv(const unsigned short* __restrict__ qkvb,
                                                    unsigned short* __restrict__ kt,
                                                    unsigned short* __restrict__ vt) {
  __shared__ unsigned short tile[64][80];  // stride 160B: 16B-aligned rows
  const int nc = blockIdx.x * 64;
  const int bh = blockIdx.y;
  const int which = blockIdx.z;           // 0 -> k (col base C), 1 -> v (col base 2C)
  const int b = bh >> 4, h = bh & 15;
  const int tid = threadIdx.x;
  const unsigned short* src = qkvb + (size_t)(b * SEQ + nc) * NQKV + (which + 1) * DIMC + h * HDIM;
  for (int idx = tid; idx < 512; idx += 256) {
    int rr = idx >> 3, ss = (idx & 7) * 8;
    *(uint4*)&tile[rr][ss] = *(const uint4*)&src[(size_t)rr * NQKV + ss];
  }
  __syncthreads();
  unsigned short* dst = (which ? vt : kt) + (size_t)bh * HDIM * SEQ;
  for (int idx = tid; idx < 512; idx += 256) {
    int dd = idx >> 3, ns = (idx & 7) * 8;
    alignas(16) unsigned short tmp[8];
#pragma unroll
    for (int jj = 0; jj < 8; ++jj) tmp[jj] = tile[ns + jj][dd];
    *(uint4*)&dst[(size_t)dd * SEQ + nc + ns] = *(const uint4*)tmp;
  }
}

// ------------- per-(b,h): G,P via MFMA + mk,mv + 4 GD iters -> W (bf16), b -------------
__global__ __launch_bounds__(256) void stats_gd(const unsigned short* __restrict__ kt,
                                                const unsigned short* __restrict__ vt,
                                                unsigned short* __restrict__ Wfb,
                                                float* __restrict__ bvec) {
  __shared__ float Gs[64][68];
  __shared__ float Ps[64][68];
  __shared__ float Ws[64][68];
  __shared__ float mkp[4][64], mvp[4][64];
  __shared__ float mks[64], mvs[64], bs[64];

  const int bh = blockIdx.x;
  const int tid = threadIdx.x;
  const int lane = tid & 63, wave = tid >> 6;
  const unsigned short* kb = kt + (size_t)bh * HDIM * SEQ;
  const unsigned short* vb = vt + (size_t)bh * HDIM * SEQ;
  const int frow = lane & 15;
  const int fk = (lane >> 4) * 8;

  f32x4 accG[4], accP[4];
#pragma unroll
  for (int j = 0; j < 4; ++j) {
    accG[j] = f32x4{0.f, 0.f, 0.f, 0.f};
    accP[j] = f32x4{0.f, 0.f, 0.f, 0.f};
  }
  for (int nb = 0; nb < SEQ; nb += 32) {
    bf16x8 af = *(const bf16x8*)&kb[(size_t)(wave * 16 + frow) * SEQ + nb + fk];  // i-tile = wave
    bf16x8 kf[4], vf[4];
#pragma unroll
    for (int j = 0; j < 4; ++j)
      kf[j] = *(const bf16x8*)&kb[(size_t)(j * 16 + frow) * SEQ + nb + fk];
#pragma unroll
    for (int j = 0; j < 4; ++j)
      vf[j] = *(const bf16x8*)&vb[(size_t)(j * 16 + frow) * SEQ + nb + fk];
#pragma unroll
    for (int j = 0; j < 4; ++j) {
      accG[j] = __builtin_amdgcn_mfma_f32_16x16x32_bf16(af, kf[j], accG[j], 0, 0, 0);
      accP[j] = __builtin_amdgcn_mfma_f32_16x16x32_bf16(af, vf[j], accP[j], 0, 0, 0);
    }
  }
  const float invN = 1.0f / (float)SEQ;
  const int orow = wave * 16 + (lane >> 4) * 4;
#pragma unroll
  for (int j = 0; j < 4; ++j)
#pragma unroll
    for (int r = 0; r < 4; ++r) {
      Gs[orow + r][j * 16 + frow] = accG[j][r] * invN;
      Ps[orow + r][j * 16 + frow] = accP[j][r] * invN;
    }

  {
    float sk_ = 0.f, sv_ = 0.f;
    const unsigned short* kr = &kb[(size_t)lane * SEQ + wave * 256];
    const unsigned short* vr = &vb[(size_t)lane * SEQ + wave * 256];
    for (int nn = 0; nn < 256; nn += 8) {
      uint4 a = *(const uint4*)&kr[nn];
      uint4 c = *(const uint4*)&vr[nn];
      const unsigned short* pa = (const unsigned short*)&a;
      const unsigned short* pc = (const unsigned short*)&c;
#pragma unroll
      for (int jj = 0; jj < 8; ++jj) { sk_ += b2f(pa[jj]); sv_ += b2f(pc[jj]); }
    }
    mkp[wave][lane] = sk_;
    mvp[wave][lane] = sv_;
  }
  __syncthreads();

  const int r = tid >> 2;
  const int c0 = (tid & 3) * 16;
  if (tid < 64) {
    mks[tid] = (mkp[0][tid] + mkp[1][tid] + mkp[2][tid] + mkp[3][tid]) * invN;
    mvs[tid] = (mvp[0][tid] + mvp[1][tid] + mvp[2][tid] + mvp[3][tid]) * invN;
    bs[tid] = 0.f;
  }
#pragma unroll
  for (int c = 0; c < 16; ++c) Ws[r][c0 + c] = 0.f;
  __syncthreads();

  for (int it = 0; it < 4; ++it) {
    float wn[16];
#pragma unroll
    for (int c = 0; c < 16; ++c)
      wn[c] = Ws[r][c0 + c] + Ps[r][c0 + c] - mks[r] * bs[c0 + c];
    for (int j = 0; j < 64; ++j) {
      float g = Gs[r][j];
#pragma unroll
      for (int c = 0; c < 16; ++c) wn[c] -= g * Ws[j][c0 + c];
    }
    float bn = 0.f;
    if (tid < 64) {
      bn = mvs[tid];
      for (int j = 0; j < 64; ++j) bn -= mks[j] * Ws[j][tid];
    }
    __syncthreads();
#pragma unroll
    for (int c = 0; c < 16; ++c) Ws[r][c0 + c] = wn[c];
    if (tid < 64) bs[tid] = bn;
    __syncthreads();
  }

  // emit W forward-layout bf16: Wfb[bh][j][dd] = W[j][dd]
  unsigned short* wout = Wfb + (size_t)bh * HDIM * HDIM;
#pragma unroll
  for (int c = 0; c < 16; ++c)
    wout[(size_t)r * HDIM + c0 + c] = f2b(Ws[r][c0 + c]);
  if (tid < 64) bvec[(size_t)bh * HDIM + tid] = bs[tid];
}

// ------------- WcT[b][p][h*64+j] = sum_dd W[b,h][j][dd] * wpT[p][h*64+dd] -------------
__global__ __launch_bounds__(256) void wc_build(const unsigned short* __restrict__ wpT,
                                                const unsigned short* __restrict__ Wfb,
                                                unsigned short* __restrict__ WcT) {
  const int bh = blockIdx.x;          // 128
  const int pblk = blockIdx.y;        // 4
  const int b = bh >> 4, h = bh & 15;
  const int tid = threadIdx.x;
  const int lane = tid & 63, wave = tid >> 6;
  const int frow = lane & 15, g4 = lane >> 4, fk = g4 * 8;
  const int p0 = pblk * 256 + wave * 64;

  f32x4 acc[4][4];
#pragma unroll
  for (int i = 0; i < 4; ++i)
#pragma unroll
    for (int j = 0; j < 4; ++j) acc[i][j] = f32x4{0.f, 0.f, 0.f, 0.f};

  const unsigned short* wb = Wfb + (size_t)bh * 4096;
#pragma unroll
  for (int kk = 0; kk < 2; ++kk) {
    bf16x8 af[4], bq[4];
#pragma unroll
    for (int i = 0; i < 4; ++i)
      af[i] = *(const bf16x8*)&wpT[(size_t)(p0 + i * 16 + frow) * 1024 + h * 64 + kk * 32 + fk];
#pragma unroll
    for (int j = 0; j < 4; ++j)
      bq[j] = *(const bf16x8*)&wb[(size_t)(j * 16 + frow) * 64 + kk * 32 + fk];
#pragma unroll
    for (int i = 0; i < 4; ++i)
#pragma unroll
      for (int j = 0; j < 4; ++j)
        acc[i][j] = __builtin_amdgcn_mfma_f32_16x16x32_bf16(bq[j], af[i], acc[i][j], 0, 0, 0);
  }

  unsigned short* dst = WcT + (size_t)b * 1024 * 1024;
#pragma unroll
  for (int i = 0; i < 4; ++i)
#pragma unroll
    for (int j = 0; j < 4; ++j) {
      ushort4 o; o.x = f2b(acc[i][j][0]); o.y = f2b(acc[i][j][1]);
      o.z = f2b(acc[i][j][2]); o.w = f2b(acc[i][j][3]);
      *(ushort4*)&dst[(size_t)(p0 + i * 16 + frow) * 1024 + h * 64 + j * 16 + g4 * 4] = o;
    }
}

// ------------- bc two-stage: part[cc][b][p] = sum_{c in chunk} bvec[b][c]*wp[c][p] -------------
__global__ __launch_bounds__(256) void bc_part(const float* __restrict__ wp,
                                               const float* __restrict__ bvec,
                                               float* __restrict__ part) {
  const int p  = blockIdx.x * 256 + threadIdx.x;   // 4 blocks in x
  const int cc = blockIdx.y;                       // 16 chunks of 64
  float s[8];
#pragma unroll
  for (int b = 0; b < 8; ++b) s[b] = 0.f;
  const int c0 = cc * 64;
  for (int c = c0; c < c0 + 64; ++c) {
    float w = wp[(size_t)c * 1024 + p];
#pragma unroll
    for (int b = 0; b < 8; ++b) s[b] += bvec[b * 1024 + c] * w;
  }
  float* dst = part + (size_t)cc * 8192;
#pragma unroll
  for (int b = 0; b < 8; ++b) dst[b * 1024 + p] = s[b];
}

// bc[b][p] = b_proj[p] + sum_cc part[cc][b][p]
__global__ __launch_bounds__(256) void bc_reduce(const float* __restrict__ part,
                                                 const float* __restrict__ b_proj,
                                                 float* __restrict__ bc) {
  const int idx = blockIdx.x * 256 + threadIdx.x;  // 32 blocks -> 8192
  const int p = idx & 1023;
  float s = b_proj[p];
#pragma unroll
  for (int cc = 0; cc < 16; ++cc) s += part[(size_t)cc * 8192 + idx];
  bc[idx] = s;
}

extern "C" void kernel_launch(void* const* d_in, const int* in_sizes, int n_in,
                              void* d_out, int out_size, void* d_ws, size_t ws_size,
                              hipStream_t stream) {
  const float* x      = (const float*)d_in[0];
  const float* w_qkv  = (const float*)d_in[1];
  const float* w_proj = (const float*)d_in[2];
  const float* b_proj = (const float*)d_in[3];

  // workspace layout (bytes)
  char* ws = (char*)d_ws;
  unsigned short* xb    = (unsigned short*)(ws + 0);          //  16,777,216
  unsigned short* wqT   = (unsigned short*)(ws + 16777216);   //   6,291,456
  unsigned short* wpT   = (unsigned short*)(ws + 23068672);   //   2,097,152
  unsigned short* qkvb  = (unsigned short*)(ws + 25165824);   //  50,331,648
  unsigned short* kt    = (unsigned short*)(ws + 75497472);   //  16,777,216
  unsigned short* vt    = (unsigned short*)(ws + 92274688);   //  16,777,216
  unsigned short* WcT   = (unsigned short*)(ws + 109051904);  //  16,777,216
  unsigned short* Wfb   = (unsigned short*)(ws + 125829120);  //   1,048,576
  float*          bvec  = (float*)(ws + 126877696);           //      32,768
  float*          bc    = (float*)(ws + 126910464);           //      32,768
  float*          bpart = (float*)(ws + 126943232);           //     524,288
  if (ws_size < (size_t)127467520) return;  // clean fail if workspace too small

  hipFuncSetAttribute((const void*)g_qkv, hipFuncAttributeMaxDynamicSharedMemorySize, 73728);
  hipFuncSetAttribute((const void*)g_out, hipFuncAttributeMaxDynamicSharedMemorySize, 61440);

  cvt_bf16<<<8192, 256, 0, stream>>>(x, xb, MROWS * DIMC / 4);
  transpose_cvt<<<dim3(96, 32), dim3(32, 8), 0, stream>>>(w_qkv, wqT, 1024, 3072);
  transpose_cvt<<<dim3(32, 32), dim3(32, 8), 0, stream>>>(w_proj, wpT, 1024, 1024);
  // qkv = xb @ wqT^T : M=8192, N=3072 -> 64*12 = 768 blocks (128x256 tiles)
  g_qkv<<<dim3(768), dim3(512), 73728, stream>>>(xb, wqT, qkvb, nullptr, NQKV, 12);
  transpose_kv<<<dim3(16, 128, 2), 256, 0, stream>>>(qkvb, kt, vt);
  stats_gd<<<128, 256, 0, stream>>>(kt, vt, Wfb, bvec);
  wc_build<<<dim3(128, 4), 256, 0, stream>>>(wpT, Wfb, WcT);
  bc_part<<<dim3(4, 16), 256, 0, stream>>>(w_proj, bvec, bpart);
  bc_reduce<<<32, 256, 0, stream>>>(bpart, b_proj, bc);
  // out = q @ WcT_b^T + bc_b : M=8192, N=1024 -> 128*4 = 512 blocks (64x256)
  g_out<<<dim3(512), dim3(256), 61440, stream>>>(qkvb, WcT, d_out, bc, DIMC, 4);
}

// Round 14
// 166.754 us; speedup vs baseline: 1.2721x; 1.2721x over previous
//
#include <hip/hip_runtime.h>

// MTTT attention, MI355X gfx950.
// B=8, N=1024, C=1024, H=16, d=64, INNER_ITR=4, INNER_LR=1.0
//
// Algebra: inner GD loop needs only G=k^Tk/N, P=k^Tv/N, mk, mv:
//   W <- W + P - G*W - mk (x) b ;  b <- mv - mk*W   (old W,b on RHS)
// Fusion (r9): out = q·Wc_b + bc_b with Wc_{b,h} = W_{b,h} @ wp_h,
//   bc_b = b_proj + sum_c b_b[c]*wp[c,:]
// r14: tail fusion — transpose_kv deleted (stats_gd stages k,v from qkvb
//   via LDS transpose), means via MFMA-ones, prep kernels merged,
//   bc_part folded into wc_build. 10 launches -> 6.

#define SEQ    1024
#define NBATCH 8
#define DIMC   1024
#define NHEAD  16
#define HDIM   64
#define MROWS  8192      // NBATCH*SEQ
#define NQKV   3072
#define KDS    136       // LDS row stride (shorts): 272B = 16B-aligned, conflict-free

typedef __attribute__((ext_vector_type(8))) __bf16 bf16x8;
typedef __attribute__((ext_vector_type(4))) float  f32x4;

__device__ __forceinline__ unsigned short f2b(float f) {
  union { float f; unsigned int u; } v; v.f = f;
  unsigned int r = (v.u + 0x7FFFu + ((v.u >> 16) & 1u)) >> 16; // RNE
  return (unsigned short)r;
}
__device__ __forceinline__ float b2f(unsigned short u) {
  union { unsigned int u; float f; } v; v.u = ((unsigned int)u) << 16;
  return v.f;
}

// async global->LDS, 16B per lane; LDS dest = wave-uniform base + lane*16
__device__ __forceinline__ void load_lds16(const void* g, void* l) {
  __builtin_amdgcn_global_load_lds(
      (__attribute__((address_space(1))) void*)(void*)(g),
      (__attribute__((address_space(3))) void*)(l), 16, 0, 0);
}

#define FENCE asm volatile("" ::: "memory")
#define BAR   __builtin_amdgcn_s_barrier()

// ---------- prep: fp32->bf16 cvt (x) + transposed cvt (w_qkv, w_proj) ----------
__global__ __launch_bounds__(256) void prep(const float* __restrict__ x,
                                            const float* __restrict__ wq,
                                            const float* __restrict__ wp,
                                            unsigned short* __restrict__ xb,
                                            unsigned short* __restrict__ wqT,
                                            unsigned short* __restrict__ wpT) {
  __shared__ unsigned short tile[32][33];
  const int bid = blockIdx.x, tid = threadIdx.x;
  if (bid < 8192) {                     // cvt x (8192*256 float4 = 32MB fp32)
    int i = bid * 256 + tid;
    float4 v = ((const float4*)x)[i];
    ushort4 o;
    o.x = f2b(v.x); o.y = f2b(v.y); o.z = f2b(v.z); o.w = f2b(v.w);
    ((ushort4*)xb)[i] = o;
    return;
  }
  const float* in; unsigned short* out; int R, Cc, tix;
  if (bid < 8192 + 3072) { tix = bid - 8192; in = wq; out = wqT; R = 1024; Cc = 3072; }
  else                   { tix = bid - 8192 - 3072; in = wp; out = wpT; R = 1024; Cc = 1024; }
  const int nbx = Cc / 32;
  const int c0 = (tix % nbx) * 32, r0 = (tix / nbx) * 32;
  const int tx = tid & 31, ty = tid >> 5;
  for (int i = ty; i < 32; i += 8)
    tile[i][tx] = f2b(in[(size_t)(r0 + i) * Cc + c0 + tx]);
  __syncthreads();
  for (int i = ty; i < 32; i += 8)
    out[(size_t)(c0 + i) * R + r0 + tx] = tile[tx][i];
}

// =====================================================================
// Occupancy-first NT bf16 GEMM body, K fixed at 1024 (r8 structure,
// fixed swizzle).  C[m][n] = sum_k A[m][k]*BT[n][k]
// =====================================================================
template <int BM, int BN, int WM, int WN, int ASTRIDE, int BMODE, int PERB>
__device__ __forceinline__
void gemm_r3(const unsigned short* __restrict__ A,
             const unsigned short* __restrict__ BT,
             void* __restrict__ Cout,
             const float* __restrict__ bias,
             int N, int NBN) {
  constexpr int THREADS = WM * WN * 64;
  constexpr int TR      = THREADS / 4;        // 64B rows covered per call
  constexpr int ABYTES  = BM * 64;            // A K-tile bytes
  constexpr int TBYTES  = (BM + BN) * 64;     // A+B K-tile bytes
  constexpr int CALLS   = TBYTES / (THREADS * 16);
  constexpr int NT      = 32;                 // K / 32

  extern __shared__ __align__(16) char ldsb[];

  const int tid  = threadIdx.x;
  const int lane = tid & 63, wave = tid >> 6;
  const int wr = wave / WN, wc = wave % WN;
  const int frow = lane & 15, g4 = lane >> 4;
  const int cz = (g4 ^ ((frow >> 1) & 3)) * 16;

  const int cpx = gridDim.x >> 3;
  const int wg  = (blockIdx.x & 7) * cpx + (blockIdx.x >> 3);
  const int bm = wg / NBN, bn = wg % NBN;
  const size_t m0 = (size_t)bm * BM, n0 = (size_t)bn * BN;

  const unsigned short* BTb = PERB ? (BT + (m0 >> 10) * (size_t)(1024 * 1024)) : BT;

  const int trow = tid >> 2;
  const int scol = ((tid & 3) ^ ((tid >> 3) & 3)) * 8;
  const unsigned short* psrc[CALLS];
#pragma unroll
  for (int c = 0; c < CALLS; ++c) {
    const int rr = c * TR + trow;
    psrc[c] = (rr < BM) ? (A + (m0 + rr) * (size_t)ASTRIDE + scol)
                        : (BTb + (size_t)(n0 + rr - BM) * 1024 + scol);
  }

  f32x4 acc[4][4];
  if (BMODE == 2) {
    const float* bp = bias + (m0 >> 10) * (size_t)N;
#pragma unroll
    for (int j = 0; j < 4; ++j) {
      float4 bv = *(const float4*)&bp[n0 + wc * 64 + j * 16 + g4 * 4];
      f32x4 t; t[0] = bv.x; t[1] = bv.y; t[2] = bv.z; t[3] = bv.w;
#pragma unroll
      for (int i = 0; i < 4; ++i) acc[i][j] = t;
    }
  } else {
#pragma unroll
    for (int i = 0; i < 4; ++i)
#pragma unroll
      for (int j = 0; j < 4; ++j) acc[i][j] = f32x4{0.f, 0.f, 0.f, 0.f};
  }

  auto stage = [&](int tk, int buf) {
    char* base = ldsb + buf * TBYTES + wave * 1024;
#pragma unroll
    for (int c = 0; c < CALLS; ++c)
      load_lds16(psrc[c] + tk * 32, base + c * (THREADS * 16));
  };

  const int aoff = (wr * 64 + frow) * 64 + cz;
  const int boff = ABYTES + (wc * 64 + frow) * 64 + cz;

  stage(0, 0); stage(1, 1);
  asm volatile("s_waitcnt vmcnt(%0)" :: "i"(CALLS) : "memory");
  FENCE; BAR;

  int bcur = 0, bpre = 2;
#pragma unroll 1
  for (int t = 0; t < NT; ++t) {
    if (t + 2 < NT) stage(t + 2, bpre);
    const char* rb = ldsb + bcur * TBYTES;
    bf16x8 af[4], bq[4];
#pragma unroll
    for (int i = 0; i < 4; ++i) af[i] = *(const bf16x8*)(rb + aoff + i * 1024);
#pragma unroll
    for (int j = 0; j < 4; ++j) bq[j] = *(const bf16x8*)(rb + boff + j * 1024);
#pragma unroll
    for (int i = 0; i < 4; ++i)
#pragma unroll
      for (int j = 0; j < 4; ++j)
        acc[i][j] = __builtin_amdgcn_mfma_f32_16x16x32_bf16(bq[j], af[i],
                                                            acc[i][j], 0, 0, 0);
    if (t + 2 < NT) asm volatile("s_waitcnt vmcnt(%0)" :: "i"(CALLS) : "memory");
    else            asm volatile("s_waitcnt vmcnt(0)" ::: "memory");
    FENCE; BAR;
    bcur = (bcur == 2) ? 0 : bcur + 1;
    bpre = (bpre == 2) ? 0 : bpre + 1;
  }

  const size_t mbase = m0 + wr * 64 + frow;
  const size_t nbase = n0 + wc * 64 + g4 * 4;
  if (BMODE == 2) {
    float* C = (float*)Cout;
#pragma unroll
    for (int i = 0; i < 4; ++i)
#pragma unroll
      for (int j = 0; j < 4; ++j) {
        float4 o; o.x = acc[i][j][0]; o.y = acc[i][j][1];
        o.z = acc[i][j][2]; o.w = acc[i][j][3];
        *(float4*)&C[(mbase + i * 16) * N + nbase + j * 16] = o;
      }
  } else {
    unsigned short* C = (unsigned short*)Cout;
#pragma unroll
    for (int i = 0; i < 4; ++i)
#pragma unroll
      for (int j = 0; j < 4; ++j) {
        ushort4 o; o.x = f2b(acc[i][j][0]); o.y = f2b(acc[i][j][1]);
        o.z = f2b(acc[i][j][2]); o.w = f2b(acc[i][j][3]);
        *(ushort4*)&C[(mbase + i * 16) * N + nbase + j * 16] = o;
      }
  }
}

__global__ __launch_bounds__(512, 4) void g_qkv(const unsigned short* __restrict__ A,
                                                const unsigned short* __restrict__ BT,
                                                void* __restrict__ C,
                                                const float* __restrict__ bias, int N, int NBN) {
  gemm_r3<128, 256, 2, 4, 1024, 0, 0>(A, BT, C, bias, N, NBN);
}
__global__ __launch_bounds__(256, 4) void g_out(const unsigned short* __restrict__ A,
                                                const unsigned short* __restrict__ BT,
                                                void* __restrict__ C,
                                                const float* __restrict__ bias, int N, int NBN) {
  gemm_r3<64, 256, 1, 4, NQKV, 2, 1>(A, BT, C, bias, N, NBN);
}

// ------------- per-(b,h): stage k,v from qkvb (LDS transpose), G,P,mk,mv
//               via MFMA (+ones operand), 4 GD iters -> W (bf16), b -------------
__global__ __launch_bounds__(256) void stats_gd(const unsigned short* __restrict__ qkvb,
                                                unsigned short* __restrict__ Wfb,
                                                float* __restrict__ bvec) {
  __shared__ float Gs[64][68];
  __shared__ float Ps[64][68];
  __shared__ float Ws[64][68];
  __shared__ unsigned short kd[64][KDS];
  __shared__ unsigned short vd[64][KDS];
  __shared__ float mks[64], mvs[64], bs[64];

  const int bh = blockIdx.x, b = bh >> 4, h = bh & 15;
  const int tid = threadIdx.x;
  const int lane = tid & 63, wave = tid >> 6;
  const int frow = lane & 15;
  const int fk = (lane >> 4) * 8;

  // global k,v bases: element [n][d] at kg[n*3072 + d]
  const unsigned short* kg = qkvb + (size_t)b * 1024 * 3072 + 1024 + h * 64;
  const unsigned short* vg = qkvb + (size_t)b * 1024 * 3072 + 2048 + h * 64;

  // ones operand (bf16 1.0 = 0x3F80, exact)
  typedef __attribute__((ext_vector_type(8))) unsigned short u16x8;
  u16x8 onesu = {0x3F80, 0x3F80, 0x3F80, 0x3F80, 0x3F80, 0x3F80, 0x3F80, 0x3F80};
  const bf16x8 ones = __builtin_bit_cast(bf16x8, onesu);

  f32x4 accG[4], accP[4], accK1, accV1;
#pragma unroll
  for (int j = 0; j < 4; ++j) {
    accG[j] = f32x4{0.f, 0.f, 0.f, 0.f};
    accP[j] = f32x4{0.f, 0.f, 0.f, 0.f};
  }
  accK1 = f32x4{0.f, 0.f, 0.f, 0.f};
  accV1 = f32x4{0.f, 0.f, 0.f, 0.f};

  const int sd = tid & 63;      // staging: this thread's d
  const int ng = tid >> 6;      // staging: n-quarter of the chunk

  for (int ch = 0; ch < 8; ++ch) {
    __syncthreads();            // prior k-steps' LDS reads complete
    const int nb0 = ch * 128 + ng * 32;
#pragma unroll
    for (int s = 0; s < 4; ++s) {
      alignas(16) unsigned short tk[8], tv[8];
#pragma unroll
      for (int t = 0; t < 8; ++t) {
        tk[t] = kg[(size_t)(nb0 + s * 8 + t) * 3072 + sd];  // lane-coalesced in sd
        tv[t] = vg[(size_t)(nb0 + s * 8 + t) * 3072 + sd];
      }
      *(uint4*)&kd[sd][ng * 32 + s * 8] = *(const uint4*)tk;
      *(uint4*)&vd[sd][ng * 32 + s * 8] = *(const uint4*)tv;
    }
    __syncthreads();
#pragma unroll
    for (int ks = 0; ks < 4; ++ks) {
      const int nb = ks * 32 + fk;
      bf16x8 afk = *(const bf16x8*)&kd[wave * 16 + frow][nb];
      bf16x8 afv = *(const bf16x8*)&vd[wave * 16 + frow][nb];
      bf16x8 kf[4], vf[4];
#pragma unroll
      for (int j = 0; j < 4; ++j) {
        kf[j] = *(const bf16x8*)&kd[j * 16 + frow][nb];
        vf[j] = *(const bf16x8*)&vd[j * 16 + frow][nb];
      }
#pragma unroll
      for (int j = 0; j < 4; ++j) {
        accG[j] = __builtin_amdgcn_mfma_f32_16x16x32_bf16(afk, kf[j], accG[j], 0, 0, 0);
        accP[j] = __builtin_amdgcn_mfma_f32_16x16x32_bf16(afk, vf[j], accP[j], 0, 0, 0);
      }
      accK1 = __builtin_amdgcn_mfma_f32_16x16x32_bf16(afk, ones, accK1, 0, 0, 0);
      accV1 = __builtin_amdgcn_mfma_f32_16x16x32_bf16(afv, ones, accV1, 0, 0, 0);
    }
  }

  const float invN = 1.0f / (float)SEQ;
  const int orow = wave * 16 + (lane >> 4) * 4;
#pragma unroll
  for (int j = 0; j < 4; ++j)
#pragma unroll
    for (int r = 0; r < 4; ++r) {
      Gs[orow + r][j * 16 + frow] = accG[j][r] * invN;
      Ps[orow + r][j * 16 + frow] = accP[j][r] * invN;
    }
  if (frow == 0) {
#pragma unroll
    for (int r = 0; r < 4; ++r) {
      mks[orow + r] = accK1[r] * invN;   // all D-cols equal for ones-B
      mvs[orow + r] = accV1[r] * invN;
    }
  }
  const int r = tid >> 2;
  const int c0 = (tid & 3) * 16;
  if (tid < 64) bs[tid] = 0.f;
#pragma unroll
  for (int c = 0; c < 16; ++c) Ws[r][c0 + c] = 0.f;
  __syncthreads();

  // 4 GD iterations:  Wn = W + P - G*W - mk (x) b ;  bn = mv - mk*W
  for (int it = 0; it < 4; ++it) {
    float wn[16];
#pragma unroll
    for (int c = 0; c < 16; ++c)
      wn[c] = Ws[r][c0 + c] + Ps[r][c0 + c] - mks[r] * bs[c0 + c];
    for (int j = 0; j < 64; ++j) {
      float g = Gs[r][j];
#pragma unroll
      for (int c = 0; c < 16; ++c) wn[c] -= g * Ws[j][c0 + c];
    }
    float bn = 0.f;
    if (tid < 64) {
      bn = mvs[tid];
      for (int j = 0; j < 64; ++j) bn -= mks[j] * Ws[j][tid];
    }
    __syncthreads();
#pragma unroll
    for (int c = 0; c < 16; ++c) Ws[r][c0 + c] = wn[c];
    if (tid < 64) bs[tid] = bn;
    __syncthreads();
  }

  // emit W forward-layout bf16: Wfb[bh][j][dd] = W[j][dd]
  unsigned short* wout = Wfb + (size_t)bh * HDIM * HDIM;
#pragma unroll
  for (int c = 0; c < 16; ++c)
    wout[(size_t)r * HDIM + c0 + c] = f2b(Ws[r][c0 + c]);
  if (tid < 64) bvec[(size_t)bh * HDIM + tid] = bs[tid];
}

// ------------- wc_build (y<4): WcT[b][p][h*64+j] = sum_dd W[b,h][j][dd]*wpT[p][h*64+dd]
//               (y==4, x<64): bc_part[cc][b][p] partial sums -------------
__global__ __launch_bounds__(256) void wc_build(const unsigned short* __restrict__ wpT,
                                                const unsigned short* __restrict__ Wfb,
                                                unsigned short* __restrict__ WcT,
                                                const float* __restrict__ wp,
                                                const float* __restrict__ bvec,
                                                float* __restrict__ part) {
  const int tid = threadIdx.x;
  if (blockIdx.y == 4) {                 // bc_part section
    if (blockIdx.x >= 64) return;
    const int p  = (blockIdx.x & 3) * 256 + tid;
    const int cc = blockIdx.x >> 2;      // 16 chunks of 64
    float s[8];
#pragma unroll
    for (int b = 0; b < 8; ++b) s[b] = 0.f;
    const int c0 = cc * 64;
    for (int c = c0; c < c0 + 64; ++c) {
      float w = wp[(size_t)c * 1024 + p];
#pragma unroll
      for (int b = 0; b < 8; ++b) s[b] += bvec[b * 1024 + c] * w;
    }
    float* dst = part + (size_t)cc * 8192;
#pragma unroll
    for (int b = 0; b < 8; ++b) dst[b * 1024 + p] = s[b];
    return;
  }
  const int bh = blockIdx.x;          // 128
  const int pblk = blockIdx.y;        // 4
  const int b = bh >> 4, h = bh & 15;
  const int lane = tid & 63, wave = tid >> 6;
  const int frow = lane & 15, g4 = lane >> 4, fk = g4 * 8;
  const int p0 = pblk * 256 + wave * 64;

  f32x4 acc[4][4];
#pragma unroll
  for (int i = 0; i < 4; ++i)
#pragma unroll
    for (int j = 0; j < 4; ++j) acc[i][j] = f32x4{0.f, 0.f, 0.f, 0.f};

  const unsigned short* wb = Wfb + (size_t)bh * 4096;
#pragma unroll
  for (int kk = 0; kk < 2; ++kk) {
    bf16x8 af[4], bq[4];
#pragma unroll
    for (int i = 0; i < 4; ++i)
      af[i] = *(const bf16x8*)&wpT[(size_t)(p0 + i * 16 + frow) * 1024 + h * 64 + kk * 32 + fk];
#pragma unroll
    for (int j = 0; j < 4; ++j)
      bq[j] = *(const bf16x8*)&wb[(size_t)(j * 16 + frow) * 64 + kk * 32 + fk];
#pragma unroll
    for (int i = 0; i < 4; ++i)
#pragma unroll
      for (int j = 0; j < 4; ++j)
        acc[i][j] = __builtin_amdgcn_mfma_f32_16x16x32_bf16(bq[j], af[i], acc[i][j], 0, 0, 0);
  }

  unsigned short* dst = WcT + (size_t)b * 1024 * 1024;
#pragma unroll
  for (int i = 0; i < 4; ++i)
#pragma unroll
    for (int j = 0; j < 4; ++j) {
      ushort4 o; o.x = f2b(acc[i][j][0]); o.y = f2b(acc[i][j][1]);
      o.z = f2b(acc[i][j][2]); o.w = f2b(acc[i][j][3]);
      *(ushort4*)&dst[(size_t)(p0 + i * 16 + frow) * 1024 + h * 64 + j * 16 + g4 * 4] = o;
    }
}

// bc[b][p] = b_proj[p] + sum_cc part[cc][b][p]
__global__ __launch_bounds__(256) void bc_reduce(const float* __restrict__ part,
                                                 const float* __restrict__ b_proj,
                                                 float* __restrict__ bc) {
  const int idx = blockIdx.x * 256 + threadIdx.x;  // 32 blocks -> 8192
  const int p = idx & 1023;
  float s = b_proj[p];
#pragma unroll
  for (int cc = 0; cc < 16; ++cc) s += part[(size_t)cc * 8192 + idx];
  bc[idx] = s;
}

extern "C" void kernel_launch(void* const* d_in, const int* in_sizes, int n_in,
                              void* d_out, int out_size, void* d_ws, size_t ws_size,
                              hipStream_t stream) {
  const float* x      = (const float*)d_in[0];
  const float* w_qkv  = (const float*)d_in[1];
  const float* w_proj = (const float*)d_in[2];
  const float* b_proj = (const float*)d_in[3];

  // workspace layout (bytes)
  char* ws = (char*)d_ws;
  unsigned short* xb    = (unsigned short*)(ws + 0);          //  16,777,216
  unsigned short* wqT   = (unsigned short*)(ws + 16777216);   //   6,291,456
  unsigned short* wpT   = (unsigned short*)(ws + 23068672);   //   2,097,152
  unsigned short* qkvb  = (unsigned short*)(ws + 25165824);   //  50,331,648
  unsigned short* WcT   = (unsigned short*)(ws + 109051904);  //  16,777,216
  unsigned short* Wfb   = (unsigned short*)(ws + 125829120);  //   1,048,576
  float*          bvec  = (float*)(ws + 126877696);           //      32,768
  float*          bc    = (float*)(ws + 126910464);           //      32,768
  float*          bpart = (float*)(ws + 126943232);           //     524,288
  if (ws_size < (size_t)127467520) return;  // clean fail if workspace too small

  hipFuncSetAttribute((const void*)g_qkv, hipFuncAttributeMaxDynamicSharedMemorySize, 73728);
  hipFuncSetAttribute((const void*)g_out, hipFuncAttributeMaxDynamicSharedMemorySize, 61440);

  // prep: cvt x (8192 blocks) + transpose-cvt wq (3072) + wp (1024)
  prep<<<dim3(8192 + 3072 + 1024), 256, 0, stream>>>(x, w_qkv, w_proj, xb, wqT, wpT);
  // qkv = xb @ wqT^T : M=8192, N=3072 -> 64*12 = 768 blocks (128x256 tiles)
  g_qkv<<<dim3(768), dim3(512), 73728, stream>>>(xb, wqT, qkvb, nullptr, NQKV, 12);
  // per-(b,h) stats + GD (reads k,v straight from qkvb)
  stats_gd<<<128, 256, 0, stream>>>(qkvb, Wfb, bvec);
  // wc_build (y<4) + bc_part (y==4)
  wc_build<<<dim3(128, 5), 256, 0, stream>>>(wpT, Wfb, WcT, w_proj, bvec, bpart);
  bc_reduce<<<32, 256, 0, stream>>>(bpart, b_proj, bc);
  // out = q @ WcT_b^T + bc_b : M=8192, N=1024 -> 128*4 = 512 blocks (64x256)
  g_out<<<dim3(512), dim3(256), 61440, stream>>>(qkvb, WcT, d_out, bc, DIMC, 4);
}